// Round 1
// 752.374 us; speedup vs baseline: 1.0619x; 1.0619x over previous
//
#include <hip/hip_runtime.h>
#include <stdint.h>

// Biaffine: out[b,x,y,o] = sum_ij in1[b,x,i] w1[i,o,j] in2[b,y,j]
//                        + p1[b,x,o] + p2[b,y,o] + bias[o]
// B=8 L=256 D=512 O=128.
// Plan: bf16 MFMA two-stage GEMM through T[b,x,o,j], chunked over b in d_ws.
// R1: double-buffered LDS + prefetch-next-K-step-before-compute (catalog T3
//     "minimum 2-phase"): kills the per-K-step vmcnt(0) latency drain that
//     left MfmaUtil at 11.6% with HBM at 35% (stall-dominated).

typedef unsigned short u16;
typedef __attribute__((ext_vector_type(8))) __bf16 bf16x8;
typedef __attribute__((ext_vector_type(4))) float f32x4;

__device__ __forceinline__ u16 f2bf(float f) {
    uint32_t u = __builtin_bit_cast(uint32_t, f);
    u += 0x7fffu + ((u >> 16) & 1u);       // RNE
    return (u16)(u >> 16);
}

// ---------------------------------------------------------------- cvt f32->bf16
__global__ __launch_bounds__(256) void cvt_kernel(const float* __restrict__ src,
                                                  u16* __restrict__ dst) {
    int i = blockIdx.x * 256 + threadIdx.x;      // one float4 each
    float4 v = reinterpret_cast<const float4*>(src)[i];
    uint2 r;
    r.x = (uint32_t)f2bf(v.x) | ((uint32_t)f2bf(v.y) << 16);
    r.y = (uint32_t)f2bf(v.z) | ((uint32_t)f2bf(v.w) << 16);
    reinterpret_cast<uint2*>(dst)[i] = r;
}

// ------------------------------------------------- w1 [i][n] f32 -> Wt [n][i] bf16
__global__ __launch_bounds__(256) void transw_kernel(const float* __restrict__ w1,
                                                     u16* __restrict__ Wt) {
    __shared__ float tile[64][65];               // +1 pad: conflict-free col reads
    const int n0 = blockIdx.x * 64;
    const int i0 = blockIdx.y * 64;
    const int t  = threadIdx.x;
    #pragma unroll
    for (int r = 0; r < 16; ++r) {
        int idx = r * 256 + t;
        int li = idx >> 6, ln = idx & 63;        // coalesced rows of w1
        tile[li][ln] = w1[(size_t)(i0 + li) * 65536 + n0 + ln];
    }
    __syncthreads();
    #pragma unroll
    for (int r = 0; r < 16; ++r) {
        int idx = r * 256 + t;
        int ln = idx >> 6, li = idx & 63;        // coalesced rows of Wt
        Wt[(size_t)(n0 + ln) * 512 + i0 + li] = f2bf(tile[li][ln]);
    }
}

// ------------------------------------------- p1/p2: rank-1 terms  p[b,l,o] (f32)
__global__ __launch_bounds__(128) void pk_kernel(const float* __restrict__ in1,
                                                 const float* __restrict__ in2,
                                                 const float* __restrict__ w2,
                                                 float* __restrict__ p1,
                                                 float* __restrict__ p2) {
    const int grp = blockIdx.x;                  // 8 rows of (b*L) per block
    const float* src; const float* w; float* dst;
    if (blockIdx.y == 0) { src = in1; w = w2;               dst = p1; }
    else                 { src = in2; w = w2 + 512 * 128;   dst = p2; }
    src += (size_t)grp * 8 * 512;
    dst += (size_t)grp * 8 * 128;
    __shared__ float rows[8][512];
    const int t = threadIdx.x;                   // 128 threads = one o each
    #pragma unroll
    for (int r = 0; r < 32; ++r) {
        int idx = r * 128 + t;
        rows[idx >> 9][idx & 511] = src[idx];
    }
    __syncthreads();
    float acc[8] = {0, 0, 0, 0, 0, 0, 0, 0};
    for (int k = 0; k < 512; ++k) {
        float wv = w[k * 128 + t];               // coalesced; L2-resident
        #pragma unroll
        for (int r = 0; r < 8; ++r) acc[r] += rows[r][k] * wv;
    }
    #pragma unroll
    for (int r = 0; r < 8; ++r) dst[r * 128 + t] = acc[r];
}

// ---------------------------------------------------------------- GEMM core
// C(128x128) += A(128xK) * B(128xK)^T, both bf16 row-major K-contiguous, K=512.
// 256 thr = 4 waves in 2x2; per wave 4x4 MFMA 16x16x32 bf16.
// Double-buffered LDS (2 x 32KB): K-step t+1's global_load_lds are issued
// BEFORE computing K-step t, so HBM latency overlaps MFMA+ds_read instead of
// being drained serially. One vmcnt(0)+barrier per K-step.
// Chunk index XOR-swizzled so fragment ds_read_b128 is 2-way-max bank aliased.
__device__ __forceinline__ void gemm_core_128(const u16* __restrict__ A,
                                              const u16* __restrict__ B,
                                              int lda, int ldb,
                                              f32x4 acc[4][4], u16* lds) {
    const int tid  = threadIdx.x;
    const int lane = tid & 63;
    const int w    = tid >> 6;
    const int wm   = w >> 1, wn = w & 1;

    // staging map: LDS chunk c holds (m = c>>3, kc = (c&7) ^ (m&7))
    int sm[4], sko[4];
    #pragma unroll
    for (int it = 0; it < 4; ++it) {
        int c  = (w * 4 + it) * 64 + lane;
        int m  = c >> 3;
        sm[it]  = m;
        sko[it] = ((c & 7) ^ (m & 7)) * 8;       // element offset in row
    }
    const int fm  = lane & 15;
    const int fkg = lane >> 4;

    auto stage = [&](int k0, u16* buf) {
        #pragma unroll
        for (int it = 0; it < 4; ++it) {
            const u16* ga = A + (size_t)sm[it] * lda + (k0 + sko[it]);
            __builtin_amdgcn_global_load_lds(
                (const __attribute__((address_space(1))) void*)ga,
                (__attribute__((address_space(3))) void*)(buf + (w * 4 + it) * 512),
                16, 0, 0);
        }
        #pragma unroll
        for (int it = 0; it < 4; ++it) {
            const u16* gb = B + (size_t)sm[it] * ldb + (k0 + sko[it]);
            __builtin_amdgcn_global_load_lds(
                (const __attribute__((address_space(1))) void*)gb,
                (__attribute__((address_space(3))) void*)(buf + 8192 + (w * 4 + it) * 512),
                16, 0, 0);
        }
    };

    // prologue: fill buffer 0
    stage(0, lds);
    __builtin_amdgcn_s_waitcnt(0);
    __syncthreads();

    #pragma unroll
    for (int k0 = 0; k0 < 512; k0 += 64) {
        u16* cur = lds + (((k0 >> 6) & 1) ? 16384 : 0);
        u16* nxt = lds + (((k0 >> 6) & 1) ? 0 : 16384);

        // issue next K-step's loads first — they complete under this compute
        if (k0 < 448) stage(k0 + 64, nxt);

        const u16* ldsA = cur;          // A chunks: 1024 * 16B = 16KB
        const u16* ldsB = cur + 8192;   // B chunks

        #pragma unroll
        for (int ks = 0; ks < 2; ++ks) {
            bf16x8 af[4], bfr[4];
            #pragma unroll
            for (int mt = 0; mt < 4; ++mt) {
                int m  = wm * 64 + mt * 16 + fm;
                int kc = ks * 4 + fkg;
                int ch = m * 8 + (kc ^ (m & 7));
                af[mt] = *reinterpret_cast<const bf16x8*>(ldsA + ch * 8);
            }
            #pragma unroll
            for (int nt = 0; nt < 4; ++nt) {
                int n  = wn * 64 + nt * 16 + fm;
                int kc = ks * 4 + fkg;
                int ch = n * 8 + (kc ^ (n & 7));
                bfr[nt] = *reinterpret_cast<const bf16x8*>(ldsB + ch * 8);
            }
            #pragma unroll
            for (int mt = 0; mt < 4; ++mt)
                #pragma unroll
                for (int nt = 0; nt < 4; ++nt)
                    acc[mt][nt] = __builtin_amdgcn_mfma_f32_16x16x32_bf16(
                        af[mt], bfr[nt], acc[mt][nt], 0, 0, 0);
        }

        // drain prefetched loads (had the whole compute phase to land) + flip
        __builtin_amdgcn_s_waitcnt(0);
        __syncthreads();
    }
}

// ------------------------------------------ stage 1: T[m][n] = Ab * Wt^T (bf16)
__global__ __launch_bounds__(256) void gemm1_kernel(const u16* __restrict__ Ab,
                                                    const u16* __restrict__ Wt,
                                                    u16* __restrict__ T) {
    __shared__ u16 lds[32768];                    // 2 x 32KB double buffer
    const int    m0 = blockIdx.x * 128;           // x-rows within chunk
    const size_t n0 = (size_t)blockIdx.y * 128;   // n = o*512+j
    f32x4 acc[4][4];
    #pragma unroll
    for (int i = 0; i < 4; ++i)
        #pragma unroll
        for (int j = 0; j < 4; ++j) acc[i][j] = f32x4{0.f, 0.f, 0.f, 0.f};
    gemm_core_128(Ab + (size_t)m0 * 512, Wt + n0 * 512, 512, 512, acc, lds);

    const int lane = threadIdx.x & 63;
    const int w = threadIdx.x >> 6;
    const int wm = w >> 1, wn = w & 1;
    const int col = lane & 15, row4 = (lane >> 4) * 4;
    #pragma unroll
    for (int mt = 0; mt < 4; ++mt)
        #pragma unroll
        for (int nt = 0; nt < 4; ++nt) {
            size_t n = n0 + wn * 64 + nt * 16 + col;
            #pragma unroll
            for (int r = 0; r < 4; ++r) {
                int m = m0 + wm * 64 + mt * 16 + row4 + r;
                T[(size_t)m * 65536 + n] = f2bf(acc[mt][nt][r]);
            }
        }
}

// --------------------- stage 2: out[b,x,y,o] = T[(x,o),:]·in2[b,y,:] + epilogue
__global__ __launch_bounds__(256) void gemm2_kernel(const u16* __restrict__ Tc,
                                                    const u16* __restrict__ B2c,
                                                    const float* __restrict__ p1c,
                                                    const float* __restrict__ p2c,
                                                    const float* __restrict__ bias,
                                                    float* __restrict__ outc) {
    __shared__ u16 lds[32768];                    // 2 x 32KB double buffer
    const int n0 = blockIdx.x * 128;              // y tile
    const int x  = blockIdx.y;                    // m2-tile == x (128 o's)
    const int bb = blockIdx.z;

    const u16* A2 = Tc  + (size_t)bb * 16777216 + (size_t)x * 65536;
    const u16* B2 = B2c + (size_t)bb * 131072  + (size_t)n0 * 512;
    f32x4 acc[4][4];
    #pragma unroll
    for (int i = 0; i < 4; ++i)
        #pragma unroll
        for (int j = 0; j < 4; ++j) acc[i][j] = f32x4{0.f, 0.f, 0.f, 0.f};
    gemm_core_128(A2, B2, 512, 512, acc, lds);

    const float* p1b = p1c + (size_t)bb * 32768 + x * 128;   // index by o
    const float* p2b = p2c + (size_t)bb * 32768;             // index y*128+o
    float* outb = outc + (size_t)bb * 8388608 + (size_t)x * 32768;

    const int lane = threadIdx.x & 63;
    const int w = threadIdx.x >> 6;
    const int wm = w >> 1, wn = w & 1;
    const int col = lane & 15, row4 = (lane >> 4) * 4;

    #pragma unroll
    for (int mt = 0; mt < 4; ++mt) {
        const int ob = wm * 64 + mt * 16 + row4;             // o base (mult 4)
        const f32x4 pv1 = *reinterpret_cast<const f32x4*>(p1b + ob);
        const f32x4 bv  = *reinterpret_cast<const f32x4*>(bias + ob);
        #pragma unroll
        for (int nt = 0; nt < 4; ++nt) {
            const int y = n0 + wn * 64 + nt * 16 + col;
            const f32x4 pv2 = *reinterpret_cast<const f32x4*>(p2b + (size_t)y * 128 + ob);
            f32x4 v = acc[mt][nt] + pv1 + pv2 + bv;
            *reinterpret_cast<f32x4*>(outb + (size_t)y * 128 + ob) = v;  // 16B store
        }
    }
}

// ----------------------------------------------------------------------- launch
extern "C" void kernel_launch(void* const* d_in, const int* in_sizes, int n_in,
                              void* d_out, int out_size, void* d_ws, size_t ws_size,
                              hipStream_t stream) {
    const float* in1 = (const float*)d_in[0];   // 8*256*512
    const float* in2 = (const float*)d_in[1];
    const float* w1  = (const float*)d_in[2];   // 512*128*512
    const float* w2  = (const float*)d_in[3];   // 1025*128
    float* out = (float*)d_out;
    char*  ws  = (char*)d_ws;

    // workspace layout (bytes)
    u16*   Wt  = (u16*)(ws);                    // 67,108,864  bf16 [n][i]
    u16*   Ab  = (u16*)(ws + 67108864);         //  2,097,152  bf16 in1
    u16*   B2b = (u16*)(ws + 69206016);         //  2,097,152  bf16 in2
    float* p1  = (float*)(ws + 71303168);       //  1,048,576
    float* p2  = (float*)(ws + 72351744);       //  1,048,576
    u16*   T   = (u16*)(ws + 73400320);         //  C * 33,554,432

    const size_t base = 73400320ull;
    int C = 1;                                   // batches per chunk
    if      (ws_size >= base + 8ull * 33554432ull) C = 8;
    else if (ws_size >= base + 4ull * 33554432ull) C = 4;
    else if (ws_size >= base + 2ull * 33554432ull) C = 2;

    cvt_kernel<<<1024, 256, 0, stream>>>(in1, Ab);
    cvt_kernel<<<1024, 256, 0, stream>>>(in2, B2b);
    transw_kernel<<<dim3(1024, 8), 256, 0, stream>>>(w1, Wt);
    pk_kernel<<<dim3(256, 2), 128, 0, stream>>>(in1, in2, w2, p1, p2);

    for (int b0 = 0; b0 < 8; b0 += C) {
        // stage 1: M = C*256 (rows = (bb,x)), N = 65536, K = 512
        gemm1_kernel<<<dim3(2 * C, 512), 256, 0, stream>>>(
            Ab + (size_t)b0 * 131072, Wt, T);
        // stage 2: per bb batch: M = 32768 (x,o), N = 256 (y), K = 512
        gemm2_kernel<<<dim3(2, 256, C), 256, 0, stream>>>(
            T, B2b + (size_t)b0 * 131072,
            p1 + (size_t)b0 * 32768, p2 + (size_t)b0 * 32768,
            w2 + 131072, out + (size_t)b0 * 8388608);
    }
}